// Round 10
// baseline (117.633 us; speedup 1.0000x reference)
//
#include <hip/hip_runtime.h>
#include <cstdint>

#define SCALE_F 0.35355339059327373f
#define EPS_F 1e-6f

typedef float v2f __attribute__((ext_vector_type(2)));

// ---- VALU cross-lane primitives (DPP / permlane) ----
template <int CTRL>
__device__ __forceinline__ float dppf(float s) {   // fetch via DPP pattern CTRL
    return __int_as_float(__builtin_amdgcn_update_dpp(
        0, __float_as_int(s), CTRL, 0xF, 0xF, true));
}
template <int PAT>
__device__ __forceinline__ float swz(float s) {    // ds_swizzle fetch (DS pipe)
    return __int_as_float(__builtin_amdgcn_ds_swizzle(__float_as_int(s), PAT));
}
// x[l] + x[l^32] via permlane32_swap (selection-convention-independent)
__device__ __forceinline__ float bf32s(float x) {
    auto r = __builtin_amdgcn_permlane32_swap(__float_as_int(x), __float_as_int(x),
                                              false, false);
    return __int_as_float(r[0]) + __int_as_float(r[1]);
}
__device__ __forceinline__ float bf32m(float x) {
    auto r = __builtin_amdgcn_permlane32_swap(__float_as_int(x), __float_as_int(x),
                                              false, false);
    return fmaxf(__int_as_float(r[0]), __int_as_float(r[1]));
}
#define DPP_X1 0xB1    // quad_perm [1,0,3,2] : exact l^1
#define DPP_X2 0x4E    // quad_perm [2,3,0,1] : exact l^2
#define DPP_R8 0x128   // row_ror:8          : exact l^8 (within 16-lane row)
#define DPP_HM 0x141   // row_half_mirror    : l^7 within each octet
#define SWZ_X16 0x401F // ds_swizzle xor 16

// raw barrier: drain LDS ops only -- global prefetch loads stay in flight
#define BARRIER() do { \
    asm volatile("s_waitcnt lgkmcnt(0)" ::: "memory"); \
    __builtin_amdgcn_s_barrier(); \
    asm volatile("" ::: "memory"); \
} while (0)

// per-row body. Weights are pre-permuted so slot i of lane l = channel (l^M[i])&7
// with M={0,7,2,5,1,6,3,4}; the transpose-reduce is then UNIFORM (no cndmask):
//   r1[i] = pd[i] + X1(pd[i+4]);  r2[i] = r1[i] + X2(r1[i+2]);  dv = r2[0] + HM(r2[1])
// and lane l ends holding channel l&7 (octet-summed); xor8/16/32 finish the wave.
// pd/weights are float2 ext-vectors -> v_pk_fma_f32 (halves the FMA stream).
#define ROW_BODY(R, BUF, PREFETCH) do { \
    const v2f e01 = {v[R].x, v[R].y}; \
    const v2f e23 = {v[R].z, v[R].w}; \
    PREFETCH; \
    { v2f sq = e01 * e01 + e23 * e23; ssv[R] = sq.x + sq.y; } \
    v2f pd2[4]; \
    _Pragma("unroll") \
    for (int c = 0; c < 4; ++c) { \
        pd2[c] = e01.x * wr2[c]; \
        pd2[c] += e01.y * wr2[4 + c]; \
        pd2[c] += e23.x * wr2[8 + c]; \
        pd2[c] += e23.y * wr2[12 + c]; \
    } \
    float r1[4]; \
    _Pragma("unroll") \
    for (int i = 0; i < 4; ++i) \
        r1[i] = pd2[i >> 1][i & 1] + dppf<DPP_X1>(pd2[2 + (i >> 1)][i & 1]); \
    float r2[2]; \
    _Pragma("unroll") \
    for (int i = 0; i < 2; ++i) \
        r2[i] = r1[i] + dppf<DPP_X2>(r1[i + 2]); \
    float dv = r2[0] + dppf<DPP_HM>(r2[1]); \
    dv += dppf<DPP_R8>(dv); \
    dv += swz<SWZ_X16>(dv); \
    dv = bf32s(dv); \
    if (lane < 8) red[BUF][R][w][lane] = dv; \
} while (0)

// one transpose-reduce collapses all 8 rows' sumsq partials (R8-verified form)
#define SS_REDUCE(BUF) do { \
    float r1[4]; \
    _Pragma("unroll") \
    for (int i = 0; i < 4; ++i) { \
        float keep = (lane & 1) ? ssv[i + 4] : ssv[i]; \
        float send = (lane & 1) ? ssv[i] : ssv[i + 4]; \
        r1[i] = keep + dppf<DPP_X1>(send); \
    } \
    float r2[2]; \
    _Pragma("unroll") \
    for (int i = 0; i < 2; ++i) { \
        float keep = (lane & 2) ? r1[i + 2] : r1[i]; \
        float send = (lane & 2) ? r1[i] : r1[i + 2]; \
        r2[i] = keep + dppf<DPP_X2>(send); \
    } \
    float keep = (lane & 4) ? r2[1] : r2[0]; \
    float send = (lane & 4) ? r2[0] : r2[1]; \
    float sv = keep + swz<0x101F>(send); \
    sv += dppf<DPP_R8>(sv); \
    sv += swz<SWZ_X16>(sv); \
    sv = bf32s(sv); \
    if (lane < 8) red[BUF][chan][w][8] = sv; \
} while (0)

// ---- pre-kernel: build per-lane-permuted weight table pw[2][512][32] ----
__global__ void permute_w_kernel(const float* __restrict__ Wq,
                                 const float* __restrict__ Wk,
                                 float* __restrict__ pw) {
    const int idx = blockIdx.x * 256 + threadIdx.x;  // 0..32767
    const int m = idx >> 14;
    const int t = (idx >> 5) & 511;
    const int s = idx & 31;
    const int j = s >> 3;
    const int i = s & 7;
    const int M[8] = {0, 7, 2, 5, 1, 6, 3, 4};
    const int h = (t & 7) ^ M[i];
    const float* src = m ? Wk : Wq;
    pw[idx] = src[(4 * t + j) * 8 + h];
}

// 512 threads/block, 16 positions/block. Thread t owns elements [4t,4t+4).
// Phase 1: 16 x-rows (2 batches of 8) with permuted-Wq slice in regs -> q
// vectors in LDS; wr2 reloaded with permuted-Wk; phase 2 streams 16x8 key
// rows with cross-barrier prefetch + raw s_barrier (no vmcnt drain).
__global__ __launch_bounds__(512, 4)
void router_kernel(const float* __restrict__ x, const float* __restrict__ bax,
                   const float* __restrict__ pw, const float* __restrict__ bq,
                   const float* __restrict__ bk, float* __restrict__ out,
                   int positions) {
    __shared__ float red[2][8][8][13];  // [parity][row][wave][chan 0..7, ss at 8, pad]
    __shared__ float qls[16][8];        // per-position query vectors

    const int t = threadIdx.x;    // 0..511
    const int w = t >> 6;         // wave 0..7
    const int lane = t & 63;
    const int chan = ((lane & 1) << 2) | (lane & 2) | ((lane & 4) >> 2);
    const long pmax = positions - 1;
    const long pb = (long)blockIdx.x * 16;

    const float4* x4 = (const float4*)x + t;     // + p*512 per row
    const float4* b4 = (const float4*)bax + t;   // + (p*8+r)*512 per row

    // ---- weight slice (phase 1: permuted Wq), float2 pairs for pk-fma ----
    v2f wr2[16];
    {
        const float4* q4 = (const float4*)(pw + 32 * t);
#pragma unroll
        for (int j = 0; j < 8; ++j) {
            float4 a = q4[j];
            wr2[2 * j + 0] = (v2f){a.x, a.y};
            wr2[2 * j + 1] = (v2f){a.z, a.w};
        }
    }
    const float bqh = bq[lane & 7];
    const float bkh = bk[lane & 7];

    float4 v[8];
    float ssv[8];

    // prologue: phase-1 batch 0 (x rows of positions pb..pb+7)
#pragma unroll
    for (int r = 0; r < 8; ++r) {
        long p = pb + r; if (p > pmax) p = pmax;
        v[r] = x4[p * 512];
    }

    // ---------- PHASE 1, batch 0 ----------
#pragma unroll
    for (int r = 0; r < 8; ++r) {
        long p = pb + 8 + r; if (p > pmax) p = pmax;
        ROW_BODY(r, 0, v[r] = x4[p * 512]);
    }
    SS_REDUCE(0);
    BARRIER();
    if (w == 0) {   // q vectors for positions pb..pb+7
        const int pr = lane >> 3, h = lane & 7;
        float dt = 0.f, ss = 0.f;
#pragma unroll
        for (int wv = 0; wv < 8; ++wv) {
            dt += red[0][pr][wv][h];
            ss += red[0][pr][wv][8];
        }
        qls[pr][h] = fmaf(dt, rsqrtf(ss + EPS_F), bqh);
    }

    // ---------- PHASE 1, batch 1 (prefetch = phase-2 iter 0 key rows) ----------
    {
        long p0 = pb; if (p0 > pmax) p0 = pmax;
#pragma unroll
        for (int r = 0; r < 8; ++r) {
            ROW_BODY(r, 1, v[r] = b4[(p0 * 8 + r) * 512]);
        }
    }
    SS_REDUCE(1);
    // reload wr2 <- permuted Wk slice (wq dead; no peak-pressure overlap)
    {
        const float4* k4 = (const float4*)(pw + 16384 + 32 * t);
#pragma unroll
        for (int j = 0; j < 8; ++j) {
            float4 a = k4[j];
            wr2[2 * j + 0] = (v2f){a.x, a.y};
            wr2[2 * j + 1] = (v2f){a.z, a.w};
        }
    }
    BARRIER();
    if (w == 0) {   // q vectors for positions pb+8..pb+15
        const int pr = lane >> 3, h = lane & 7;
        float dt = 0.f, ss = 0.f;
#pragma unroll
        for (int wv = 0; wv < 8; ++wv) {
            dt += red[1][pr][wv][h];
            ss += red[1][pr][wv][8];
        }
        qls[8 + pr][h] = fmaf(dt, rsqrtf(ss + EPS_F), bqh);
    }

    // ---------- PHASE 2: 16 positions x 8 key rows ----------
#pragma unroll 1
    for (int j = 0; j < 16; ++j) {
        const int bf = j & 1;
        long p = pb + j; if (p > pmax) p = pmax;
        long pn = pb + j + 1; if (pn > pmax) pn = pmax;
        const bool pref = (j < 15);
#pragma unroll
        for (int r = 0; r < 8; ++r) {
            ROW_BODY(r, bf, if (pref) v[r] = b4[(pn * 8 + r) * 512]);
        }
        SS_REDUCE(bf);
        BARRIER();
        if (w == 0) {
            const int kn = lane >> 3, hh = lane & 7;
            float dtk = 0.f, ssk = 0.f;
#pragma unroll
            for (int wv = 0; wv < 8; ++wv) {
                dtk += red[bf][kn][wv][hh];
                ssk += red[bf][kn][wv][8];
            }
            float kval = fmaf(dtk, rsqrtf(ssk + EPS_F), bkh);
            float qv = qls[j][hh];
            // score for key kn: sum q[h]*k[kn][h] within the octet (all VALU)
            float s = qv * kval;
            s += dppf<DPP_X1>(s);
            s += dppf<DPP_X2>(s);
            s += dppf<DPP_HM>(s);
            s *= SCALE_F;
            // softmax across the 8 key octets (lanes l, l^8, l^16, l^32)
            float mx = fmaxf(s, dppf<DPP_R8>(s));
            mx = fmaxf(mx, swz<SWZ_X16>(mx));
            mx = bf32m(mx);
            float ev = __expf(s - mx);
            float den = ev + dppf<DPP_R8>(ev);
            den += swz<SWZ_X16>(den);
            den = bf32s(den);
            if (hh == 0 && pb + j < positions) out[p * 8 + kn] = ev / den;
        }
    }
}

extern "C" void kernel_launch(void* const* d_in, const int* in_sizes, int n_in,
                              void* d_out, int out_size, void* d_ws, size_t ws_size,
                              hipStream_t stream) {
    const float* x   = (const float*)d_in[0];
    const float* bax = (const float*)d_in[1];
    const float* Wq  = (const float*)d_in[2];
    const float* bq  = (const float*)d_in[3];
    const float* Wk  = (const float*)d_in[4];
    const float* bk  = (const float*)d_in[5];
    float* out = (float*)d_out;
    float* pw  = (float*)d_ws;   // 128 KB permuted-weight table

    const int positions = in_sizes[0] / 2048;   // B*S
    permute_w_kernel<<<128, 256, 0, stream>>>(Wq, Wk, pw);
    const int nb = (positions + 15) / 16;
    router_kernel<<<nb, 512, 0, stream>>>(x, bax, pw, bq, bk, out, positions);
}

// Round 11
// 101.232 us; speedup vs baseline: 1.1620x; 1.1620x over previous
//
#include <hip/hip_runtime.h>
#include <cstdint>

#define SCALE_F 0.35355339059327373f
#define EPS_F 1e-6f

typedef float v4f __attribute__((ext_vector_type(4)));

// ---- VALU cross-lane primitives (DPP / permlane), replacing DS-pipe shuffles ----
template <int CTRL>
__device__ __forceinline__ float dppf(float s) {   // fetch via DPP pattern CTRL
    return __int_as_float(__builtin_amdgcn_update_dpp(
        0, __float_as_int(s), CTRL, 0xF, 0xF, true));
}
template <int PAT>
__device__ __forceinline__ float swz(float s) {    // ds_swizzle fetch (DS pipe)
    return __int_as_float(__builtin_amdgcn_ds_swizzle(__float_as_int(s), PAT));
}
// x[l] + x[l^32] via permlane32_swap (selection-convention-independent)
__device__ __forceinline__ float bf32s(float x) {
    auto r = __builtin_amdgcn_permlane32_swap(__float_as_int(x), __float_as_int(x),
                                              false, false);
    return __int_as_float(r[0]) + __int_as_float(r[1]);
}
__device__ __forceinline__ float bf32m(float x) {
    auto r = __builtin_amdgcn_permlane32_swap(__float_as_int(x), __float_as_int(x),
                                              false, false);
    return fmaxf(__int_as_float(r[0]), __int_as_float(r[1]));
}
#define DPP_X1 0xB1    // quad_perm [1,0,3,2] : exact l^1
#define DPP_X2 0x4E    // quad_perm [2,3,0,1] : exact l^2
#define DPP_R8 0x128   // row_ror:8          : exact l^8 (within 16-lane row)
#define DPP_HM 0x141   // row_half_mirror    : cross-quad pair within octet
#define SWZ_X4  0x101F // ds_swizzle xor 4
#define SWZ_X16 0x401F // ds_swizzle xor 16

// streaming (nontemporal) float4 load: data is read exactly once chip-wide
__device__ __forceinline__ v4f ntload(const v4f* p) {
    return __builtin_nontemporal_load(p);
}

// raw barrier: drain LDS ops only -- global prefetch loads stay in flight
#define BARRIER() do { \
    asm volatile("s_waitcnt lgkmcnt(0)" ::: "memory"); \
    __builtin_amdgcn_s_barrier(); \
    asm volatile("" ::: "memory"); \
} while (0)

// per-row: extract, prefetch into just-freed regs, sumsq, 8-col dot partials,
// transpose-reduce (DPP stages + 1 ds_swizzle) + all-VALU-dominant butterfly
#define ROW_BODY(R, BUF, PREFETCH) do { \
    const float e0 = v[R].x, e1 = v[R].y, e2 = v[R].z, e3 = v[R].w; \
    PREFETCH; \
    ssv[R] = fmaf(e3, e3, fmaf(e2, e2, fmaf(e1, e1, e0 * e0))); \
    float pd[8]; \
    _Pragma("unroll") \
    for (int h = 0; h < 8; ++h) \
        pd[h] = fmaf(e3, wreg[24 + h], fmaf(e2, wreg[16 + h], \
                 fmaf(e1, wreg[8 + h], e0 * wreg[h]))); \
    float r1[4]; \
    _Pragma("unroll") \
    for (int i = 0; i < 4; ++i) { \
        float keep = (lane & 1) ? pd[i + 4] : pd[i]; \
        float send = (lane & 1) ? pd[i] : pd[i + 4]; \
        r1[i] = keep + dppf<DPP_X1>(send); \
    } \
    float r2[2]; \
    _Pragma("unroll") \
    for (int i = 0; i < 2; ++i) { \
        float keep = (lane & 2) ? r1[i + 2] : r1[i]; \
        float send = (lane & 2) ? r1[i] : r1[i + 2]; \
        r2[i] = keep + dppf<DPP_X2>(send); \
    } \
    { \
        float keep = (lane & 4) ? r2[1] : r2[0]; \
        float send = (lane & 4) ? r2[0] : r2[1]; \
        float dv = keep + swz<SWZ_X4>(send); \
        dv += dppf<DPP_R8>(dv); \
        dv += swz<SWZ_X16>(dv); \
        dv = bf32s(dv); \
        if (lane < 8) red[BUF][R][w][chan] = dv; \
    } \
} while (0)

// one transpose-reduce collapses all 8 rows' sumsq partials
#define SS_REDUCE(BUF) do { \
    float r1[4]; \
    _Pragma("unroll") \
    for (int i = 0; i < 4; ++i) { \
        float keep = (lane & 1) ? ssv[i + 4] : ssv[i]; \
        float send = (lane & 1) ? ssv[i] : ssv[i + 4]; \
        r1[i] = keep + dppf<DPP_X1>(send); \
    } \
    float r2[2]; \
    _Pragma("unroll") \
    for (int i = 0; i < 2; ++i) { \
        float keep = (lane & 2) ? r1[i + 2] : r1[i]; \
        float send = (lane & 2) ? r1[i] : r1[i + 2]; \
        r2[i] = keep + dppf<DPP_X2>(send); \
    } \
    float keep = (lane & 4) ? r2[1] : r2[0]; \
    float send = (lane & 4) ? r2[0] : r2[1]; \
    float sv = keep + swz<SWZ_X4>(send); \
    sv += dppf<DPP_R8>(sv); \
    sv += swz<SWZ_X16>(sv); \
    sv = bf32s(sv); \
    if (lane < 8) red[BUF][chan][w][8] = sv; \
} while (0)

// 512 threads/block, 16 positions/block. Thread t owns elements [4t,4t+4).
// Phase 1: 16 x-rows (2 batches of 8) with Wq slice in regs -> q vectors in
// LDS; wreg reloaded with Wk; phase 2 streams 16x8 key rows with
// cross-barrier prefetch + raw s_barrier (no vmcnt drain). Reductions are
// DPP/permlane (VALU pipe). Data loads are NONTEMPORAL (nt): the 576 MB
// stream is read exactly once -- bypass L2 LRU, cut fill overhead.
__global__ __launch_bounds__(512, 4)
void router_kernel(const float* __restrict__ x, const float* __restrict__ bax,
                   const float* __restrict__ Wq, const float* __restrict__ bq,
                   const float* __restrict__ Wk, const float* __restrict__ bk,
                   float* __restrict__ out, int positions) {
    __shared__ float red[2][8][8][13];  // [parity][row][wave][chan 0..7, ss at 8, pad]
    __shared__ float qls[16][8];        // per-position query vectors

    const int t = threadIdx.x;    // 0..511
    const int w = t >> 6;         // wave 0..7
    const int lane = t & 63;
    const int chan = ((lane & 1) << 2) | (lane & 2) | ((lane & 4) >> 2);
    const long pmax = positions - 1;
    const long pb = (long)blockIdx.x * 16;

    const v4f* x4 = (const v4f*)x + t;     // + p*512 per row
    const v4f* b4 = (const v4f*)bax + t;   // + (p*8+r)*512 per row

    // ---- weight slice (phase 1: Wq) ----
    float wreg[32];
    {
        const float4* q4 = (const float4*)(Wq + 32 * t);
#pragma unroll
        for (int j = 0; j < 8; ++j) {
            float4 a = q4[j];
            wreg[4 * j + 0] = a.x; wreg[4 * j + 1] = a.y;
            wreg[4 * j + 2] = a.z; wreg[4 * j + 3] = a.w;
        }
    }
    const float bqh = bq[lane & 7];
    const float bkh = bk[lane & 7];

    v4f v[8];
    float ssv[8];

    // prologue: phase-1 batch 0 (x rows of positions pb..pb+7)
#pragma unroll
    for (int r = 0; r < 8; ++r) {
        long p = pb + r; if (p > pmax) p = pmax;
        v[r] = ntload(x4 + p * 512);
    }

    // ---------- PHASE 1, batch 0 ----------
#pragma unroll
    for (int r = 0; r < 8; ++r) {
        long p = pb + 8 + r; if (p > pmax) p = pmax;
        ROW_BODY(r, 0, v[r] = ntload(x4 + p * 512));
    }
    SS_REDUCE(0);
    BARRIER();
    if (w == 0) {   // q vectors for positions pb..pb+7
        const int pr = lane >> 3, h = lane & 7;
        float dt = 0.f, ss = 0.f;
#pragma unroll
        for (int wv = 0; wv < 8; ++wv) {
            dt += red[0][pr][wv][h];
            ss += red[0][pr][wv][8];
        }
        qls[pr][h] = fmaf(dt, rsqrtf(ss + EPS_F), bqh);
    }

    // ---------- PHASE 1, batch 1 (prefetch = phase-2 iter 0 key rows) ----------
    {
        long p0 = pb; if (p0 > pmax) p0 = pmax;
#pragma unroll
        for (int r = 0; r < 8; ++r) {
            ROW_BODY(r, 1, v[r] = ntload(b4 + (p0 * 8 + r) * 512));
        }
    }
    SS_REDUCE(1);
    // reload wreg <- Wk slice (wq dead; no peak-pressure overlap)
    {
        const float4* k4 = (const float4*)(Wk + 32 * t);
#pragma unroll
        for (int j = 0; j < 8; ++j) {
            float4 a = k4[j];
            wreg[4 * j + 0] = a.x; wreg[4 * j + 1] = a.y;
            wreg[4 * j + 2] = a.z; wreg[4 * j + 3] = a.w;
        }
    }
    BARRIER();
    if (w == 0) {   // q vectors for positions pb+8..pb+15
        const int pr = lane >> 3, h = lane & 7;
        float dt = 0.f, ss = 0.f;
#pragma unroll
        for (int wv = 0; wv < 8; ++wv) {
            dt += red[1][pr][wv][h];
            ss += red[1][pr][wv][8];
        }
        qls[8 + pr][h] = fmaf(dt, rsqrtf(ss + EPS_F), bqh);
    }

    // ---------- PHASE 2: 16 positions x 8 key rows ----------
#pragma unroll 1
    for (int j = 0; j < 16; ++j) {
        const int bf = j & 1;
        long p = pb + j; if (p > pmax) p = pmax;
        long pn = pb + j + 1; if (pn > pmax) pn = pmax;
        const bool pref = (j < 15);
#pragma unroll
        for (int r = 0; r < 8; ++r) {
            ROW_BODY(r, bf, if (pref) v[r] = ntload(b4 + (pn * 8 + r) * 512));
        }
        SS_REDUCE(bf);
        BARRIER();
        if (w == 0) {
            const int kn = lane >> 3, hh = lane & 7;
            float dtk = 0.f, ssk = 0.f;
#pragma unroll
            for (int wv = 0; wv < 8; ++wv) {
                dtk += red[bf][kn][wv][hh];
                ssk += red[bf][kn][wv][8];
            }
            float kval = fmaf(dtk, rsqrtf(ssk + EPS_F), bkh);
            float qv = qls[j][hh];
            // score for key kn: sum q[h]*k[kn][h] within the octet (all VALU)
            float s = qv * kval;
            s += dppf<DPP_X1>(s);
            s += dppf<DPP_X2>(s);
            s += dppf<DPP_HM>(s);   // quads uniform -> half_mirror completes octet
            s *= SCALE_F;
            // softmax across the 8 key octets (lanes l, l^8, l^16, l^32)
            float mx = fmaxf(s, dppf<DPP_R8>(s));
            mx = fmaxf(mx, swz<SWZ_X16>(mx));
            mx = bf32m(mx);
            float ev = __expf(s - mx);
            float den = ev + dppf<DPP_R8>(ev);
            den += swz<SWZ_X16>(den);
            den = bf32s(den);
            if (hh == 0 && pb + j < positions) out[p * 8 + kn] = ev / den;
        }
    }
}

extern "C" void kernel_launch(void* const* d_in, const int* in_sizes, int n_in,
                              void* d_out, int out_size, void* d_ws, size_t ws_size,
                              hipStream_t stream) {
    const float* x   = (const float*)d_in[0];
    const float* bax = (const float*)d_in[1];
    const float* Wq  = (const float*)d_in[2];
    const float* bq  = (const float*)d_in[3];
    const float* Wk  = (const float*)d_in[4];
    const float* bk  = (const float*)d_in[5];
    float* out = (float*)d_out;

    const int positions = in_sizes[0] / 2048;   // B*S
    const int nb = (positions + 15) / 16;
    router_kernel<<<nb, 512, 0, stream>>>(x, bax, Wq, bq, Wk, bk, out, positions);
}